// Round 1
// baseline (402.327 us; speedup 1.0000x reference)
//
#include <hip/hip_runtime.h>
#include <hip/hip_bf16.h>
#include <stdint.h>

#define N_TOK 2048
#define H_DIM 1024
#define F_DIM 2816
#define N_EXP 8

#define BK 64
#define LDA 72   // padded LDS row stride in bf16 elems (+8 keeps 16B align, breaks pow2 bank stride)

typedef __attribute__((ext_vector_type(8))) short bf16x8;
typedef __attribute__((ext_vector_type(4))) float f32x4;

static __device__ __forceinline__ unsigned short f2bf(float f) {
    union { float f; unsigned u; } v; v.f = f;
    unsigned r = v.u + 0x7fffu + ((v.u >> 16) & 1u);   // round-to-nearest-even
    return (unsigned short)(r >> 16);
}

// ---------------- Router: 1 wave per token ----------------
__global__ __launch_bounds__(256) void router_kernel(
    const float* __restrict__ x, const float* __restrict__ gate_w,
    int* __restrict__ counts, int* __restrict__ row_token, float* __restrict__ row_weight,
    int* __restrict__ slot_e, int* __restrict__ slot_pos)
{
    __shared__ float gsm[N_EXP * H_DIM];
    for (int i = threadIdx.x; i < N_EXP * H_DIM; i += 256) gsm[i] = gate_w[i];
    __syncthreads();

    const int wave = threadIdx.x >> 6;
    const int lane = threadIdx.x & 63;
    const int n = blockIdx.x * 4 + wave;
    if (n >= N_TOK) return;

    float xv[16];
#pragma unroll
    for (int i = 0; i < 16; i++) xv[i] = x[(size_t)n * H_DIM + lane + 64 * i];

    float logit[N_EXP];
#pragma unroll
    for (int e = 0; e < N_EXP; e++) {
        float p = 0.f;
#pragma unroll
        for (int i = 0; i < 16; i++) p += xv[i] * gsm[e * H_DIM + lane + 64 * i];
#pragma unroll
        for (int s = 32; s > 0; s >>= 1) p += __shfl_xor(p, s, 64);
        logit[e] = p;
    }

    if (lane == 0) {
        int e0 = 0; float l0 = logit[0];
#pragma unroll
        for (int e = 1; e < N_EXP; e++) if (logit[e] > l0) { l0 = logit[e]; e0 = e; }
        int e1 = -1; float l1 = -3.4e38f;
#pragma unroll
        for (int e = 0; e < N_EXP; e++) if (e != e0 && logit[e] > l1) { l1 = logit[e]; e1 = e; }
        // renormalized top-2 softmax weights (full softmax denominator cancels)
        float w0 = 1.f / (1.f + __expf(l1 - l0));
        float w1 = 1.f - w0;
        int p0 = atomicAdd(&counts[e0], 1);
        int p1 = atomicAdd(&counts[e1], 1);
        row_token[e0 * N_TOK + p0] = n;  row_weight[e0 * N_TOK + p0] = w0;
        row_token[e1 * N_TOK + p1] = n;  row_weight[e1 * N_TOK + p1] = w1;
        slot_e[n * 2 + 0] = e0;  slot_pos[n * 2 + 0] = p0;
        slot_e[n * 2 + 1] = e1;  slot_pos[n * 2 + 1] = p1;
    }
}

// ---------------- Scan: exclusive prefix over 8 counts ----------------
__global__ void scan_kernel(const int* __restrict__ counts, int* __restrict__ offsets)
{
    if (threadIdx.x == 0 && blockIdx.x == 0) {
        int acc = 0;
        for (int e = 0; e < N_EXP; e++) { offsets[e] = acc; acc += counts[e]; }
    }
}

// ---------------- Up GEMM (grouped): act = silu(X_gather @ w1[e]^T), bf16 out ----
__global__ __launch_bounds__(256) void up_gemm_kernel(
    const float* __restrict__ x, const float* __restrict__ w1,
    const int* __restrict__ counts, const int* __restrict__ offsets,
    const int* __restrict__ row_token,
    unsigned short* __restrict__ act)
{
    const int e = blockIdx.z;
    const int cnt = counts[e];
    const int mTile = blockIdx.y;
    if (mTile * 128 >= cnt) return;
    const int fTile = blockIdx.x;
    const int off = offsets[e];

    __shared__ __align__(16) unsigned short As[128 * LDA];
    __shared__ __align__(16) unsigned short Bs[128 * LDA];

    const int tid = threadIdx.x;
    const int lane = tid & 63;
    const int wave = tid >> 6;
    const int wm = (wave >> 1) * 64, wn = (wave & 1) * 64;

    int tokens[8];
#pragma unroll
    for (int j = 0; j < 8; j++) {
        int i = tid + 256 * j;
        int row = i >> 4;
        int pos = mTile * 128 + row;
        tokens[j] = row_token[e * N_TOK + min(pos, cnt - 1)];
    }

    f32x4 acc[4][4];
#pragma unroll
    for (int i = 0; i < 4; i++)
#pragma unroll
        for (int j = 0; j < 4; j++) acc[i][j] = (f32x4)(0.f);

    const float* wbase = w1 + (size_t)e * F_DIM * H_DIM + (size_t)(fTile * 128) * H_DIM;

    for (int kt = 0; kt < H_DIM / BK; kt++) {
        const int k0 = kt * BK;
#pragma unroll
        for (int j = 0; j < 8; j++) {            // stage A (gathered x rows, fp32->bf16)
            int i = tid + 256 * j;
            int row = i >> 4, c = i & 15;
            const float4 v = *(const float4*)(x + (size_t)tokens[j] * H_DIM + k0 + c * 4);
            ushort4 b; b.x = f2bf(v.x); b.y = f2bf(v.y); b.z = f2bf(v.z); b.w = f2bf(v.w);
            *(ushort4*)(As + row * LDA + c * 4) = b;
        }
#pragma unroll
        for (int j = 0; j < 8; j++) {            // stage B (w1 rows, fp32->bf16)
            int i = tid + 256 * j;
            int row = i >> 4, c = i & 15;
            const float4 v = *(const float4*)(wbase + (size_t)row * H_DIM + k0 + c * 4);
            ushort4 b; b.x = f2bf(v.x); b.y = f2bf(v.y); b.z = f2bf(v.z); b.w = f2bf(v.w);
            *(ushort4*)(Bs + row * LDA + c * 4) = b;
        }
        __syncthreads();
#pragma unroll
        for (int ks = 0; ks < BK / 32; ks++) {
            const int kloc = ks * 32 + (lane >> 4) * 8;
            bf16x8 af[4], bfr[4];
#pragma unroll
            for (int i = 0; i < 4; i++)
                af[i] = *(const bf16x8*)(As + (wm + i * 16 + (lane & 15)) * LDA + kloc);
#pragma unroll
            for (int i = 0; i < 4; i++)
                bfr[i] = *(const bf16x8*)(Bs + (wn + i * 16 + (lane & 15)) * LDA + kloc);
#pragma unroll
            for (int i = 0; i < 4; i++)
#pragma unroll
                for (int j = 0; j < 4; j++)
                    acc[i][j] = __builtin_amdgcn_mfma_f32_16x16x32_bf16(af[i], bfr[j], acc[i][j], 0, 0, 0);
        }
        __syncthreads();
    }

    // epilogue: silu + bf16 store (C/D layout: col=lane&15, row=(lane>>4)*4+reg)
#pragma unroll
    for (int i = 0; i < 4; i++) {
        const int mrow = wm + i * 16 + ((lane >> 4) << 2);
#pragma unroll
        for (int r = 0; r < 4; r++) {
            const int m = mTile * 128 + mrow + r;
            if (m < cnt) {
#pragma unroll
                for (int j = 0; j < 4; j++) {
                    float v = acc[i][j][r];
                    float s = v / (1.f + __expf(-v));
                    int col = fTile * 128 + wn + j * 16 + (lane & 15);
                    act[(size_t)(off + m) * F_DIM + col] = f2bf(s);
                }
            }
        }
    }
}

// ---------------- Down GEMM (grouped): out_slot = w * (act @ w2[e]^T) ----------
__global__ __launch_bounds__(256) void down_gemm_kernel(
    const unsigned short* __restrict__ act, const float* __restrict__ w2,
    const int* __restrict__ counts, const int* __restrict__ offsets,
    const float* __restrict__ row_weight,
    float* __restrict__ out_slot)
{
    const int e = blockIdx.z;
    const int cnt = counts[e];
    const int mTile = blockIdx.y;
    if (mTile * 128 >= cnt) return;
    const int hTile = blockIdx.x;
    const int off = offsets[e];

    __shared__ __align__(16) unsigned short As[128 * LDA];
    __shared__ __align__(16) unsigned short Bs[128 * LDA];

    const int tid = threadIdx.x;
    const int lane = tid & 63;
    const int wave = tid >> 6;
    const int wm = (wave >> 1) * 64, wn = (wave & 1) * 64;

    int rowsg[4];
#pragma unroll
    for (int j = 0; j < 4; j++) {
        int i = tid + 256 * j;
        int row = i >> 3;
        rowsg[j] = off + min(mTile * 128 + row, cnt - 1);
    }

    f32x4 acc[4][4];
#pragma unroll
    for (int i = 0; i < 4; i++)
#pragma unroll
        for (int j = 0; j < 4; j++) acc[i][j] = (f32x4)(0.f);

    const float* wbase = w2 + (size_t)e * H_DIM * F_DIM + (size_t)(hTile * 128) * F_DIM;

    for (int kt = 0; kt < F_DIM / BK; kt++) {
        const int k0 = kt * BK;
#pragma unroll
        for (int j = 0; j < 4; j++) {            // stage A (bf16 act, direct 16B copies)
            int i = tid + 256 * j;
            int row = i >> 3, c = i & 7;
            const uint4 v = *(const uint4*)(act + (size_t)rowsg[j] * F_DIM + k0 + c * 8);
            *(uint4*)(As + row * LDA + c * 8) = v;
        }
#pragma unroll
        for (int j = 0; j < 8; j++) {            // stage B (w2 rows, fp32->bf16)
            int i = tid + 256 * j;
            int row = i >> 4, c = i & 15;
            const float4 v = *(const float4*)(wbase + (size_t)row * F_DIM + k0 + c * 4);
            ushort4 b; b.x = f2bf(v.x); b.y = f2bf(v.y); b.z = f2bf(v.z); b.w = f2bf(v.w);
            *(ushort4*)(Bs + row * LDA + c * 4) = b;
        }
        __syncthreads();
#pragma unroll
        for (int ks = 0; ks < BK / 32; ks++) {
            const int kloc = ks * 32 + (lane >> 4) * 8;
            bf16x8 af[4], bfr[4];
#pragma unroll
            for (int i = 0; i < 4; i++)
                af[i] = *(const bf16x8*)(As + (wm + i * 16 + (lane & 15)) * LDA + kloc);
#pragma unroll
            for (int i = 0; i < 4; i++)
                bfr[i] = *(const bf16x8*)(Bs + (wn + i * 16 + (lane & 15)) * LDA + kloc);
#pragma unroll
            for (int i = 0; i < 4; i++)
#pragma unroll
                for (int j = 0; j < 4; j++)
                    acc[i][j] = __builtin_amdgcn_mfma_f32_16x16x32_bf16(af[i], bfr[j], acc[i][j], 0, 0, 0);
        }
        __syncthreads();
    }

#pragma unroll
    for (int i = 0; i < 4; i++) {
        const int mrow = wm + i * 16 + ((lane >> 4) << 2);
#pragma unroll
        for (int r = 0; r < 4; r++) {
            const int m = mTile * 128 + mrow + r;
            if (m < cnt) {
                const float w = row_weight[e * N_TOK + m];
#pragma unroll
                for (int j = 0; j < 4; j++) {
                    int col = hTile * 128 + wn + j * 16 + (lane & 15);
                    out_slot[(size_t)(off + m) * H_DIM + col] = w * acc[i][j][r];
                }
            }
        }
    }
}

// ---------------- Combine: y[n] = slot0 + slot1 (weights already folded) -------
__global__ __launch_bounds__(256) void combine_kernel(
    const float* __restrict__ out_slot, const int* __restrict__ offsets,
    const int* __restrict__ slot_e, const int* __restrict__ slot_pos,
    float* __restrict__ out)
{
    const int n = blockIdx.x;
    const int r0 = offsets[slot_e[n * 2 + 0]] + slot_pos[n * 2 + 0];
    const int r1 = offsets[slot_e[n * 2 + 1]] + slot_pos[n * 2 + 1];
    const int t = threadIdx.x;
    const float4 a = *(const float4*)(out_slot + (size_t)r0 * H_DIM + t * 4);
    const float4 b = *(const float4*)(out_slot + (size_t)r1 * H_DIM + t * 4);
    float4 c; c.x = a.x + b.x; c.y = a.y + b.y; c.z = a.z + b.z; c.w = a.w + b.w;
    *(float4*)(out + (size_t)n * H_DIM + t * 4) = c;
}

extern "C" void kernel_launch(void* const* d_in, const int* in_sizes, int n_in,
                              void* d_out, int out_size, void* d_ws, size_t ws_size,
                              hipStream_t stream) {
    const float* x      = (const float*)d_in[0];
    const float* gate_w = (const float*)d_in[1];
    const float* w1     = (const float*)d_in[2];
    const float* w2     = (const float*)d_in[3];
    float* out = (float*)d_out;

    char* ws = (char*)d_ws;
    size_t o = 0;
    auto alloc = [&](size_t bytes) -> void* {
        void* p = ws + o;
        o = (o + bytes + 255) & ~(size_t)255;
        return p;
    };
    int*   counts     = (int*)  alloc(N_EXP * sizeof(int));
    int*   offsets    = (int*)  alloc(N_EXP * sizeof(int));
    int*   row_token  = (int*)  alloc((size_t)N_EXP * N_TOK * sizeof(int));
    float* row_weight = (float*)alloc((size_t)N_EXP * N_TOK * sizeof(float));
    int*   slot_e     = (int*)  alloc((size_t)N_TOK * 2 * sizeof(int));
    int*   slot_pos   = (int*)  alloc((size_t)N_TOK * 2 * sizeof(int));
    unsigned short* act = (unsigned short*)alloc((size_t)N_TOK * 2 * F_DIM * sizeof(unsigned short));
    float* out_slot   = (float*)alloc((size_t)N_TOK * 2 * H_DIM * sizeof(float));

    hipMemsetAsync(counts, 0, N_EXP * sizeof(int), stream);

    router_kernel<<<N_TOK / 4, 256, 0, stream>>>(x, gate_w, counts, row_token, row_weight, slot_e, slot_pos);
    scan_kernel<<<1, 64, 0, stream>>>(counts, offsets);
    up_gemm_kernel<<<dim3(F_DIM / 128, N_TOK / 128, N_EXP), 256, 0, stream>>>(
        x, w1, counts, offsets, row_token, act);
    down_gemm_kernel<<<dim3(H_DIM / 128, N_TOK / 128, N_EXP), 256, 0, stream>>>(
        act, w2, counts, offsets, row_weight, out_slot);
    combine_kernel<<<N_TOK, 256, 0, stream>>>(out_slot, offsets, slot_e, slot_pos, out);
}